// Round 20
// baseline (42.672 us; speedup 1.0000x reference)
//
#include <hip/hip_runtime.h>
#include <hip/hip_bf16.h>
#include <hip/hip_fp8.h>

// ContrastiveLoss fused kernel for MI355X (gfx950).
//
// Math reduction (T=0.5):
//   f = x / max(||x||, 1e-8)   (rows)
//   s_ij = f_i . f_j
//   den_i = sum_{j: label_j != label_i} exp(2 s_ij)
//   loss  = sum_i [ c_i * log(den_i) - sum_{j same label, j != i} 2 s_ij ]
//           / (sum_i c_i + 1e-5),   c_i = count(label_i) - 1
//
// N=4096, D=512, labels in [0,100).
//
// Round 20: MULTI-PAIR BLOCKS + CROSS-PAIR DOUBLE-BUFFER. R16's direct
// k2 counters (occupancy 8.35% with 528 blocks -> avg block lifetime
// ~14 us vs ~3 us compute) point at per-block fixed overhead (cold
// staging wait + launch/teardown + 2-round residency) paid 528x. Fix:
// grid 256 (1 block/CU, 133 KB LDS), each block sweeps pairs u, u+256,
// (u+512): while computing pair p from Bsh[cur], the NEXT pair's whole
// 64 KB B-tile stages into Bsh[cur^1] -- staging latency hidden under
// compute, cold-paid once per block not once per pair. Two barriers per
// pair (col-flush; buffer flip -- its vmcnt drain is free, staging had
// ~3 us to finish). Pair-core/epilogue/k1/k3a bit-identical to R17
// (best, 36.74 us): fp8 e4m3 16x16x32, 8-wave blocks, zero-barrier
// inner loop, symmetric 528 tile-pairs, global atomicAdd den/pos.

typedef float floatx4 __attribute__((ext_vector_type(4)));
typedef long lng2 __attribute__((ext_vector_type(2)));
typedef unsigned int u32;
typedef unsigned char u8;

#define N_ROWS 4096
#define DIM 512
#define GRPB 8192              // bytes per 16-row fp8 fragment group (16*512)
#define EPS_NORM 1e-8f
#define EPS_DEN 1e-5f
#define TI 128                 // tile size (rows and cols)
#define NT (N_ROWS / TI)       // 32 tiles
#define NPAIR (NT * (NT + 1) / 2)   // 528 pairs
#define NSLAB 8                // 8 slabs of 16 j-rows per tile
#define KGRID 256              // k2 blocks (1 per CU)

static __device__ inline void load_lds16(const char* g, char* l) {
  __builtin_amdgcn_global_load_lds(
      (const __attribute__((address_space(1))) void*)g,
      (__attribute__((address_space(3))) void*)l, 16, 0, 0);
}

static __device__ inline void decode_pair(int u, int* ti, int* tj) {
  int b = u, t = 0, rem = NT;
  while (b >= rem) { b -= rem; ++t; --rem; }
  *ti = t; *tj = t + b;
}

// wave-per-row normalize + fp8 pack, fragment-major store; grid 1024 x 256.
// G layout (fp8): group g = row>>4 (8192 B), kt-pair p = kt>>1 (1024 B);
// consumer lane l = kq*16 + (row&15) holds fragment of kt at byte
// l*16 + (kt&1)*8, covering k = kt*32 + kq*8 .. +8.
__global__ void k1_normalize(const float* __restrict__ x,
                             const int* __restrict__ labels,
                             u8* __restrict__ G, u8* __restrict__ lab8,
                             float* __restrict__ den, float* __restrict__ pos,
                             float* __restrict__ acc2, int* __restrict__ done) {
  const int row = blockIdx.x * 4 + (threadIdx.x >> 6);
  const int lane = threadIdx.x & 63;
  const float4* src = reinterpret_cast<const float4*>(x + (size_t)row * DIM);
  float4 v0 = src[lane * 2];
  float4 v1 = src[lane * 2 + 1];
  float ss = v0.x*v0.x + v0.y*v0.y + v0.z*v0.z + v0.w*v0.w
           + v1.x*v1.x + v1.y*v1.y + v1.z*v1.z + v1.w*v1.w;
#pragma unroll
  for (int m = 1; m < 64; m <<= 1) ss += __shfl_xor(ss, m, 64);
  float scale = 1.f / fmaxf(sqrtf(ss), EPS_NORM);

  u32 lo = ((u32)__hip_fp8_e4m3(v0.x * scale).__x)
         | ((u32)__hip_fp8_e4m3(v0.y * scale).__x << 8)
         | ((u32)__hip_fp8_e4m3(v0.z * scale).__x << 16)
         | ((u32)__hip_fp8_e4m3(v0.w * scale).__x << 24);
  u32 hi = ((u32)__hip_fp8_e4m3(v1.x * scale).__x)
         | ((u32)__hip_fp8_e4m3(v1.y * scale).__x << 8)
         | ((u32)__hip_fp8_e4m3(v1.z * scale).__x << 16)
         | ((u32)__hip_fp8_e4m3(v1.w * scale).__x << 24);
  uint2 o; o.x = lo; o.y = hi;

  const int kt = lane >> 2;
  const int kq = lane & 3;
  char* dst = (char*)G + (size_t)(row >> 4) * GRPB + (kt >> 1) * 1024
            + (kq * 16 + (row & 15)) * 16 + (kt & 1) * 8;
  *reinterpret_cast<uint2*>(dst) = o;

  if (lane == 0) { den[row] = 0.f; pos[row] = 0.f; }
  if (lane == 1) lab8[row] = (u8)labels[row];
  if (blockIdx.x == 0 && threadIdx.x == 0) {
    acc2[0] = 0.f; acc2[1] = 0.f; done[0] = 0;
  }
}

// fused fp8 sim-GEMM + symmetric reduction; multi-pair blocks with
// cross-pair double-buffered whole-tile staging.
__global__ __launch_bounds__(512, 2) void k2_fused(
    const u8* __restrict__ G, const u8* __restrict__ lab8,
    float* __restrict__ den, float* __restrict__ pos) {
  __shared__ u8 Bsh[2][64 * 1024];       // 2 x whole B tile (64 x 1 KB chunks)
  __shared__ int labj_sh[2][TI];
  __shared__ float colden[TI], colpos[TI];

  const char* Gb = (const char*)G;

  const int tid = threadIdx.x;
  const int wv = tid >> 6;                // 0..7
  const int lane = tid & 63;
  const int l15 = lane & 15;
  const int kg4 = lane >> 4;              // 0..3 (16-col groups)

  // stage whole 64 KB B tile of tile-row tjv into buffer bufsel;
  // wave wv stages chunks wv*8 .. wv*8+7 (contiguous 1 KB src AND dst).
#define STAGE(bufsel, tjv) do {                                             \
    _Pragma("unroll")                                                       \
    for (int c_ = 0; c_ < 8; ++c_) {                                        \
      const int ch_ = wv * 8 + c_;                                          \
      load_lds16(Gb + (size_t)((tjv) * 8 + (ch_ >> 3)) * GRPB               \
                    + (ch_ & 7) * 1024 + lane * 16,                         \
                 (char*)Bsh[bufsel] + ch_ * 1024 + lane * 16);              \
    }                                                                       \
  } while (0)

  int u = blockIdx.x;
  int ti, tj;
  decode_pair(u, &ti, &tj);

  // prologue: stage first pair's tile; zero col accumulators
  STAGE(0, tj);
  if (tid < TI) {
    labj_sh[0][tid] = lab8[tj * TI + tid];
    colden[tid] = 0.f;
    colpos[tid] = 0.f;
  }
  __syncthreads();   // first tile staged (cold; paid once per block)

  for (int pi = 0; u < NPAIR; u += KGRID, ++pi) {
    const int cur = pi & 1;
    const bool diag = (ti == tj);
    const int ib = ti * TI;
    const int jb = tj * TI;

    // prefetch NEXT pair's whole tile into the other buffer (overlaps
    // with this pair's compute; drained by the end-of-pair barrier)
    int tin = ti, tjn = tj;
    const int un = u + KGRID;
    if (un < NPAIR) {
      decode_pair(un, &tin, &tjn);
      STAGE(cur ^ 1, tjn);
      if (tid < TI) labj_sh[cur ^ 1][tid] = lab8[tjn * TI + tid];
    }

    // A fragments: 16 rows/wave = 1 fp8 fragment group -> 32 VGPRs.
    long a[16];
    {
      const char* ab = Gb + (size_t)(ti * 8 + wv) * GRPB + lane * 16;
#pragma unroll
      for (int q = 0; q < 8; ++q) {
        lng2 v = *reinterpret_cast<const lng2*>(ab + q * 1024);
        a[2 * q] = v.x; a[2 * q + 1] = v.y;
      }
    }
#pragma unroll
    for (int kt = 0; kt < 16; ++kt)
      asm volatile("" : "+v"(a[kt]));

    // C/D layout (verified gfx950, dtype-independent): col = lane&15 (j),
    // row = kg4*4 + r (i). lane's 4 output rows: i_base + r.
    const int i_base = ib + wv * 16 + kg4 * 4;
    const u32 labp = *reinterpret_cast<const u32*>(lab8 + i_base);

    float den_acc[4] = {0.f, 0.f, 0.f, 0.f};
    float pos_acc[4] = {0.f, 0.f, 0.f, 0.f};

    // barrier-free inner loop: 8 slabs; per slab two 8-deep MFMA chains
#pragma unroll
    for (int t = 0; t < NSLAB; ++t) {
      const int jrow = jb + t * 16 + l15;
      const int labj = labj_sh[cur][t * 16 + l15];

      floatx4 acc_a = {0.f,0.f,0.f,0.f};
      floatx4 acc_b = {0.f,0.f,0.f,0.f};
      const char* bbase = (char*)Bsh[cur] + t * 8192 + lane * 16;
#pragma unroll
      for (int q = 0; q < 8; ++q) {
        lng2 b2 = *reinterpret_cast<const lng2*>(bbase + q * 1024);
        acc_a = __builtin_amdgcn_mfma_f32_16x16x32_fp8_fp8(a[2*q],   b2.x, acc_a, 0, 0, 0);
        acc_b = __builtin_amdgcn_mfma_f32_16x16x32_fp8_fp8(a[2*q+1], b2.y, acc_b, 0, 0, 0);
      }

      float cd = 0.f, cp = 0.f;   // col partials for this 16-j slab
#pragma unroll
      for (int r = 0; r < 4; ++r) {
        const int labi = (int)((labp >> (8 * r)) & 255u);
        const int irow = i_base + r;
        float s2 = 2.f * (acc_a[r] + acc_b[r]);
        float e = __expf(s2);
        bool sm = (labj == labi);
        float dv = sm ? 0.f : e;
        float pv = (sm && (jrow != irow)) ? s2 : 0.f;
        den_acc[r] += dv;
        pos_acc[r] += pv;
        cd += dv; cp += pv;
      }
      if (!diag) {
        // reduce col partials across the 4 kg groups (lanes sharing l15)
        cd += __shfl_xor(cd, 16, 64); cd += __shfl_xor(cd, 32, 64);
        cp += __shfl_xor(cp, 16, 64); cp += __shfl_xor(cp, 32, 64);
        if (kg4 == 0) {
          atomicAdd(&colden[t * 16 + l15], cd);   // LDS-scope, cheap
          atomicAdd(&colpos[t * 16 + l15], cp);
        }
      }
    }

    // row path: reduce across 16 cols (lanes with same kg4), 1 atomic/row
#pragma unroll
    for (int r = 0; r < 4; ++r) {
      float dd = den_acc[r], pp = pos_acc[r];
#pragma unroll
      for (int m = 1; m < 16; m <<= 1) {
        dd += __shfl_xor(dd, m, 64);
        pp += __shfl_xor(pp, m, 64);
      }
      if (l15 == 0) {
        atomicAdd(&den[i_base + r], dd);
        atomicAdd(&pos[i_base + r], pp);
      }
    }

    // col path flush (off-diagonal): one atomic per col, then reset
    if (!diag) {
      __syncthreads();   // all waves' LDS col atomics done
      if (tid < TI) {
        atomicAdd(&den[jb + tid], colden[tid]);
        atomicAdd(&pos[jb + tid], colpos[tid]);
        colden[tid] = 0.f;
        colpos[tid] = 0.f;
      }
    }
    __syncthreads();   // next tile staged + resets visible; flip buffers

    ti = tin; tj = tjn;
  }
#undef STAGE
}

// per-row finalize + scalar write: 16 blocks x 256 threads; last-done
// block (device atomics) computes the output. (Proven: absmax 0.)
__global__ void k3a(const float* __restrict__ den, const float* __restrict__ pos,
                    const int* __restrict__ labels, float* __restrict__ acc2,
                    int* __restrict__ done, float* __restrict__ out) {
  __shared__ int hist[128];
  __shared__ float sn[4], sz[4];
  const int tid = threadIdx.x;
  if (tid < 128) hist[tid] = 0;
  __syncthreads();
  for (int i = tid; i < N_ROWS; i += 256) atomicAdd(&hist[labels[i]], 1);
  __syncthreads();

  const int row = blockIdx.x * 256 + tid;
  int c = hist[labels[row]] - 1;
  float num = (float)c * logf(den[row]) - pos[row];
  float nnz = (float)c;
#pragma unroll
  for (int m = 1; m < 64; m <<= 1) {
    num += __shfl_xor(num, m, 64);
    nnz += __shfl_xor(nnz, m, 64);
  }
  if ((tid & 63) == 0) { sn[tid >> 6] = num; sz[tid >> 6] = nnz; }
  __syncthreads();
  if (tid == 0) {
    atomicAdd(&acc2[0], sn[0] + sn[1] + sn[2] + sn[3]);
    atomicAdd(&acc2[1], sz[0] + sz[1] + sz[2] + sz[3]);
    __threadfence();
    int old = atomicAdd(done, 1);
    if (old == 15) {
      float tn = atomicAdd(&acc2[0], 0.f);   // coherent device-scope read
      float tz = atomicAdd(&acc2[1], 0.f);
      out[0] = tn / (tz + EPS_DEN);
    }
  }
}

extern "C" void kernel_launch(void* const* d_in, const int* in_sizes, int n_in,
                              void* d_out, int out_size, void* d_ws, size_t ws_size,
                              hipStream_t stream) {
  const float* x = (const float*)d_in[0];
  const int* labels = (const int*)d_in[1];

  // ws: G fp8 (2MB) | den f32[4096] | pos f32[4096] | lab8 u8[4096]
  //   | acc2 f32[2] | done i32[1]
  u8* G = (u8*)d_ws;
  float* den = (float*)((char*)d_ws + (size_t)N_ROWS * DIM);
  float* pos = den + N_ROWS;
  u8* lab8 = (u8*)(pos + N_ROWS);
  float* acc2 = (float*)(lab8 + N_ROWS);
  int* done = (int*)(acc2 + 2);
  float* out = (float*)d_out;

  hipLaunchKernelGGL(k1_normalize, dim3(N_ROWS / 4), dim3(256), 0, stream,
                     x, labels, G, lab8, den, pos, acc2, done);
  hipLaunchKernelGGL(k2_fused, dim3(KGRID), dim3(512), 0, stream,
                     G, lab8, den, pos);
  hipLaunchKernelGGL(k3a, dim3(16), dim3(256), 0, stream,
                     den, pos, labels, acc2, done, out);
}